// Round 9
// baseline (156.893 us; speedup 1.0000x reference)
//
#include <hip/hip_runtime.h>
#include <hip/hip_bf16.h>

// out = tril((2Q - tril(QK^T)K) K^T) V per (b,h): two fused causal passes of
// Y = tril(X K^T) W  (pass0: X=Q,W=K -> o2; pass1: X=2Q-o2, W=V).
// R5: s-permuted GEMM1 A-reads keep P in registers (no LDS P round-trip);
//     diag-only causal mask; ldsK bit5 col-XOR keeps kf reads 2-way.
// R6: double-buffered K/W tiles -> ONE barrier per iteration; loads at iter
//     top, commit at iter bottom (GEMM phase covers load latency).
// R8b/c: wf reads hoisted to regs between GEMM1 and cvt; setprio around MFMA.
// R10: single-strip WGs (1024 = 32 bh x 32 strips), longest-first + dynamic
//     backfill, bh = i&31 pins a bh's strips to one XCD. 92->79 us.
// R11/R12: 2-deep prefetch regressed (scratch spill / no exposed vmcnt wait).
//     REVERTED to R10's single-deep schedule.
// R13: drop ldsS (9216 B) -> 36864 B LDS -> 4 WGs/CU (launch_bounds(256,4),
//     16 waves/CU). (a) Xf loaded directly from global: the B-frag is 16
//     contiguous bytes/lane, one-time per WG, same total bytes as staging.
//     (b) pass-seam scratch reuses ldsW[1-c] (dead at seam: last read behind
//     the iter u-1 barrier, rewritten by this iter's commit); one extra
//     block-uniform barrier between seam and commit, once per kernel.

typedef __bf16 bf16x8 __attribute__((ext_vector_type(8)));
typedef __bf16 bf16x2 __attribute__((ext_vector_type(2)));
typedef float  f32x4  __attribute__((ext_vector_type(4)));

#define MFMA16(a, b, c) __builtin_amdgcn_mfma_f32_16x16x32_bf16((a), (b), (c), 0, 0, 0)

static constexpr int S  = 2048;
static constexpr int H  = 16;
static constexpr int D  = 64;
static constexpr int RS = 3 * H * D;   // 3072 floats between consecutive s rows
static constexpr int BN = 64;          // key rows per iteration
static constexpr int LR = 72;          // row stride (u16): 64 + 8

__global__ __launch_bounds__(256, 4)
void ttt_kernel(const float* __restrict__ qkv, float* __restrict__ out)
{
    __shared__ __bf16 ldsK[2][BN * LR];   // K tile [s][d ^ 32*((s>>3)&1)], x2
    __shared__ __bf16 ldsW[2][D  * LR];   // W^T [d][s ^ (d&56)], x2
    // total 36864 B -> 4 WGs/CU

    const int tid  = threadIdx.x;
    const int wv   = tid >> 6;
    const int lane = tid & 63;
    const int q    = lane >> 4;        // quad 0..3
    const int l16  = lane & 15;

    // mapping: rank = i>>5 ascending => p descending (longest first);
    // bh = i&31 pins all strips of a bh to one XCD (i%8 == bh%8).
    const int i  = (int)blockIdx.x;
    const int p  = 31 - (i >> 5);      // t-strip index, 64-iter strips first
    const int bh = i & 31;
    const int b  = bh >> 4;
    const int h  = bh & 15;
    const int t0 = 64 * p;             // strip rows [t0, t0+64)
    const int nP = p + 1;              // s-blocks per pass

    const float* baseQ = qkv + (size_t)b * S * RS + h * D;
    const float* baseK = baseQ + H * D;
    const float* baseV = baseQ + 2 * H * D;

    // staging coords: thread owns rows r2,r2+1 cols cb..cb+7 of a 64x64 tile
    const int r2  = (tid >> 3) * 2;
    const int cb  = (tid & 7) * 8;
    const int cbK = cb ^ (((r2 >> 3) & 1) << 5);   // ldsK bit5 col swizzle

    f32x4 pk[4], pv[4];   // prefetch regs: [0..1]=row r2, [2..3]=row r2+1
    auto loadT = [&](f32x4* dst, const float* base, int s0) {
        const float* pg = base + (size_t)(s0 + r2) * RS + cb;
        dst[0] = *(const f32x4*)(pg);
        dst[1] = *(const f32x4*)(pg + 4);
        dst[2] = *(const f32x4*)(pg + RS);
        dst[3] = *(const f32x4*)(pg + RS + 4);
    };

    // commit prefetch regs -> LDS tile buffers (K always from pk; W from src)
    auto commit = [&](__bf16* K_, __bf16* W_, const f32x4* src) {
        bf16x8 w0, w1;
#pragma unroll
        for (int j = 0; j < 4; ++j) {
            w0[j] = (__bf16)pk[0][j]; w0[4 + j] = (__bf16)pk[1][j];
            w1[j] = (__bf16)pk[2][j]; w1[4 + j] = (__bf16)pk[3][j];
        }
        *(bf16x8*)(K_ + r2 * LR + cbK)       = w0;
        *(bf16x8*)(K_ + (r2 + 1) * LR + cbK) = w1;
#pragma unroll
        for (int j = 0; j < 8; ++j) {
            const int d = cb + j;
            bf16x2 w;
            w[0] = (__bf16)((j < 4) ? src[0][j & 3] : src[1][j & 3]);
            w[1] = (__bf16)((j < 4) ? src[2][j & 3] : src[3][j & 3]);
            *(bf16x2*)(W_ + d * LR + (r2 ^ (d & 56))) = w;
        }
    };

    loadT(pk, baseK, 0);   // tile 0 (pass 0: K only), in flight during Xf load

    // ---- R13a: X B-frags straight from global (no LDS staging) ----
    // lane holds X[t = t0 + wv*16 + l16][d = kt*32 + q*8 + j], 16 B/lane/kt
    bf16x8 Xf[2];   // [kt]
    const int row0 = wv * 16;
    {
        const float* pq = baseQ + (size_t)(t0 + row0 + l16) * RS + q * 8;
#pragma unroll
        for (int kt = 0; kt < 2; ++kt) {
            f32x4 f0 = *(const f32x4*)(pq + kt * 32);
            f32x4 f1 = *(const f32x4*)(pq + kt * 32 + 4);
#pragma unroll
            for (int j = 0; j < 4; ++j) {
                Xf[kt][j]     = (__bf16)f0[j];
                Xf[kt][4 + j] = (__bf16)f1[j];
            }
        }
    }

    // permuted K-row base: A-row m of tile mi reads physical K row
    //   (mi>>1)*32 + (m>>2)*8 + (mi&1)*4 + (m&3); per-lane part (m = l16):
    const int rp   = (l16 >> 2) * 8 + (l16 & 3);
    const int kcol = (q * 8) | (((l16 >> 2) & 1) << 5);   // disjoint bits

    const f32x4 zero4 = {0.f, 0.f, 0.f, 0.f};
    f32x4 Y[4];
#pragma unroll
    for (int nd = 0; nd < 4; ++nd) Y[nd] = zero4;

    const int tg = t0 + wv * 16 + l16;

    // ---- prologue: commit tile 0 into buf 0 ----
    commit(ldsK[0], ldsW[0], pk);      // vmcnt wait for pk here (one-time)
    __syncthreads();                   // buf 0 visible

    const int NT = 2 * nP;             // iterations across both passes

    for (int u = 0; u < NT; ++u) {
        const int c  = u & 1;
        const int sb = (u >= nP) ? (u - nP) : u;

        // ---- issue loads for tile u+1 (consumed by commit at iter bottom) ----
        if (u + 1 < NT) {
            const int np_ = (u + 1 >= nP) ? 1 : 0;
            const int nsb = (u + 1) - (np_ ? nP : 0);
            loadT(pk, baseK, nsb * BN);
            if (np_) loadT(pv, baseV, nsb * BN);
        }

        __bf16* K_ = ldsK[c];
        __bf16* W_ = ldsW[c];

        // ---- GEMM1-T (s-permuted): Pt[mi][r] = P[s_l][t],
        //      s_l = (mi>>1)*32 + q*8 + (mi&1)*4 + r
        f32x4 Pt[4];
#pragma unroll
        for (int mi = 0; mi < 4; ++mi) Pt[mi] = zero4;
        __builtin_amdgcn_s_setprio(1);
#pragma unroll
        for (int kt = 0; kt < 2; ++kt) {
#pragma unroll
            for (int mi = 0; mi < 4; ++mi) {
                bf16x8 kf = *(bf16x8*)(K_
                    + ((mi >> 1) * 32 + (mi & 1) * 4 + rp) * LR
                    + ((kt * 32) ^ kcol));
                Pt[mi] = MFMA16(kf, Xf[kt], Pt[mi]);
            }
        }
        __builtin_amdgcn_s_setprio(0);

        // ---- hoist wf reads (independent of GEMM1) -> stream under cvt ----
        bf16x8 wfr[2][4];
#pragma unroll
        for (int kt = 0; kt < 2; ++kt)
#pragma unroll
            for (int nd = 0; nd < 4; ++nd) {
                const int d = l16 + nd * 16;
                wfr[kt][nd] = *(bf16x8*)(W_ + d * LR + ((kt * 32 + q * 8) ^ (d & 56)));
            }

        // ---- in-register masked cvt -> GEMM2 A-frags ----
        // af[kt][b2*4+r] = P[t=l16][s = kt*32 + q*8 + b2*4 + r] (masked)
        bf16x8 af[2];
        {
            const bool diag = (sb == nP - 1);
#pragma unroll
            for (int kt = 0; kt < 2; ++kt) {
                bf16x8 a;
                if (diag) {
#pragma unroll
                    for (int b2 = 0; b2 < 2; ++b2)
#pragma unroll
                        for (int r = 0; r < 4; ++r) {
                            const int sg = sb * BN + kt * 32 + q * 8 + b2 * 4 + r;
                            a[b2 * 4 + r] = (sg <= tg) ? (__bf16)Pt[2 * kt + b2][r]
                                                       : (__bf16)0.0f;
                        }
                } else {
#pragma unroll
                    for (int b2 = 0; b2 < 2; ++b2)
#pragma unroll
                        for (int r = 0; r < 4; ++r)
                            a[b2 * 4 + r] = (__bf16)Pt[2 * kt + b2][r];
                }
                af[kt] = a;
            }
        }

        // ---- GEMM2: Y[t][d] += sum_s P[t][s] W[s][d] ----
        __builtin_amdgcn_s_setprio(1);
#pragma unroll
        for (int kt = 0; kt < 2; ++kt)
#pragma unroll
            for (int nd = 0; nd < 4; ++nd)
                Y[nd] = MFMA16(af[kt], wfr[kt][nd], Y[nd]);
        __builtin_amdgcn_s_setprio(0);

        // ---- pass seam / epilogue ----
        if (u == nP - 1) {
            // R13b: seam scratch reuses ldsW[1-c] (dead here: last read behind
            // the iter u-1 barrier; rewritten by this iter's commit below).
            // Wave-private 16-row slice; extra barrier before commit.
            __bf16* sc = ldsW[1 - c] + row0 * LR;
            // o2 (C-layout) -> scratch plain [t][d], reread as frags,
            // Xf = 2Q - o2; then reset Y.
#pragma unroll
            for (int nd = 0; nd < 4; ++nd)
#pragma unroll
                for (int r = 0; r < 4; ++r)
                    sc[(q * 4 + r) * LR + l16 + nd * 16] = (__bf16)Y[nd][r];
#pragma unroll
            for (int kt = 0; kt < 2; ++kt) {
                bf16x8 of = *(bf16x8*)(sc + l16 * LR + kt * 32 + q * 8);
#pragma unroll
                for (int j = 0; j < 8; ++j)
                    Xf[kt][j] = (__bf16)(2.0f * (float)Xf[kt][j] - (float)of[j]);
            }
#pragma unroll
            for (int nd = 0; nd < 4; ++nd) Y[nd] = zero4;
            __syncthreads();   // seam reads done before commit overwrites
        } else if (u == NT - 1) {
            // out[b][t][h][d] fp32
#pragma unroll
            for (int nd = 0; nd < 4; ++nd)
#pragma unroll
                for (int r = 0; r < 4; ++r) {
                    const int t = t0 + wv * 16 + q * 4 + r;
                    const int d = l16 + nd * 16;
                    out[(((size_t)b * S + t) * H + h) * D + d] = Y[nd][r];
                }
        }

        // ---- commit tile u+1 into the other buffer; single barrier ----
        if (u + 1 < NT) {
            commit(ldsK[1 - c], ldsW[1 - c], (u + 1 >= nP) ? pv : pk);
            __syncthreads();
        }
    }
}

extern "C" void kernel_launch(void* const* d_in, const int* in_sizes, int n_in,
                              void* d_out, int out_size, void* d_ws, size_t ws_size,
                              hipStream_t stream)
{
    const float* qkv = (const float*)d_in[0];
    float* out = (float*)d_out;
    ttt_kernel<<<dim3(1024), 256, 0, stream>>>(qkv, out);   // 32 strips x 32 bh
}

// Round 10
// 136.872 us; speedup vs baseline: 1.1463x; 1.1463x over previous
//
#include <hip/hip_runtime.h>
#include <hip/hip_bf16.h>

// out = tril((2Q - tril(QK^T)K) K^T) V per (b,h): two fused causal passes of
// Y = tril(X K^T) W  (pass0: X=Q,W=K -> o2; pass1: X=2Q-o2, W=V).
// R5: s-permuted GEMM1 A-reads keep P in registers (no LDS P round-trip);
//     diag-only causal mask; ldsK bit5 col-XOR keeps kf reads 2-way.
// R6: double-buffered K/W tiles -> ONE barrier per iteration; loads at iter
//     top, commit at iter bottom (GEMM phase covers load latency).
// R8b/c: wf reads hoisted to regs between GEMM1 and cvt; setprio around MFMA.
// R10: single-strip WGs (1024 = 32 bh x 32 strips), longest-first + dynamic
//     backfill, bh = i&31 pins a bh's strips to one XCD. 92->79 us.
// R13: 36864 B LDS (no ldsS): Xf loaded direct from global (16B/lane/kt,
//     one-time); pass-seam scratch reuses dead ldsW[1-c] + one extra barrier.
//     -> 4 WGs/CU possible. REGRESSED at launch_bounds(256,4): allocator's
//     spill-to-raise-occupancy heuristic squeezed 72->64 VGPR (8-wave bucket)
//     and spilled (WRITE_SIZE 16.4->27.6 MB) though LDS caps at 4 WG/CU.
// R14: same kernel, launch_bounds(256,3): the min-occupancy guarantee stays
//     below the natural 72-reg allocation (no squeeze, no spill), while
//     runtime residency is LDS-limited at 4 WG/CU -- the occupancy R13
//     wanted, at R10's register budget.

typedef __bf16 bf16x8 __attribute__((ext_vector_type(8)));
typedef __bf16 bf16x2 __attribute__((ext_vector_type(2)));
typedef float  f32x4  __attribute__((ext_vector_type(4)));

#define MFMA16(a, b, c) __builtin_amdgcn_mfma_f32_16x16x32_bf16((a), (b), (c), 0, 0, 0)

static constexpr int S  = 2048;
static constexpr int H  = 16;
static constexpr int D  = 64;
static constexpr int RS = 3 * H * D;   // 3072 floats between consecutive s rows
static constexpr int BN = 64;          // key rows per iteration
static constexpr int LR = 72;          // row stride (u16): 64 + 8

__global__ __launch_bounds__(256, 3)
void ttt_kernel(const float* __restrict__ qkv, float* __restrict__ out)
{
    __shared__ __bf16 ldsK[2][BN * LR];   // K tile [s][d ^ 32*((s>>3)&1)], x2
    __shared__ __bf16 ldsW[2][D  * LR];   // W^T [d][s ^ (d&56)], x2
    // total 36864 B -> LDS allows 4 WGs/CU

    const int tid  = threadIdx.x;
    const int wv   = tid >> 6;
    const int lane = tid & 63;
    const int q    = lane >> 4;        // quad 0..3
    const int l16  = lane & 15;

    // mapping: rank = i>>5 ascending => p descending (longest first);
    // bh = i&31 pins all strips of a bh to one XCD (i%8 == bh%8).
    const int i  = (int)blockIdx.x;
    const int p  = 31 - (i >> 5);      // t-strip index, 64-iter strips first
    const int bh = i & 31;
    const int b  = bh >> 4;
    const int h  = bh & 15;
    const int t0 = 64 * p;             // strip rows [t0, t0+64)
    const int nP = p + 1;              // s-blocks per pass

    const float* baseQ = qkv + (size_t)b * S * RS + h * D;
    const float* baseK = baseQ + H * D;
    const float* baseV = baseQ + 2 * H * D;

    // staging coords: thread owns rows r2,r2+1 cols cb..cb+7 of a 64x64 tile
    const int r2  = (tid >> 3) * 2;
    const int cb  = (tid & 7) * 8;
    const int cbK = cb ^ (((r2 >> 3) & 1) << 5);   // ldsK bit5 col swizzle

    f32x4 pk[4], pv[4];   // prefetch regs: [0..1]=row r2, [2..3]=row r2+1
    auto loadT = [&](f32x4* dst, const float* base, int s0) {
        const float* pg = base + (size_t)(s0 + r2) * RS + cb;
        dst[0] = *(const f32x4*)(pg);
        dst[1] = *(const f32x4*)(pg + 4);
        dst[2] = *(const f32x4*)(pg + RS);
        dst[3] = *(const f32x4*)(pg + RS + 4);
    };

    // commit prefetch regs -> LDS tile buffers (K always from pk; W from src)
    auto commit = [&](__bf16* K_, __bf16* W_, const f32x4* src) {
        bf16x8 w0, w1;
#pragma unroll
        for (int j = 0; j < 4; ++j) {
            w0[j] = (__bf16)pk[0][j]; w0[4 + j] = (__bf16)pk[1][j];
            w1[j] = (__bf16)pk[2][j]; w1[4 + j] = (__bf16)pk[3][j];
        }
        *(bf16x8*)(K_ + r2 * LR + cbK)       = w0;
        *(bf16x8*)(K_ + (r2 + 1) * LR + cbK) = w1;
#pragma unroll
        for (int j = 0; j < 8; ++j) {
            const int d = cb + j;
            bf16x2 w;
            w[0] = (__bf16)((j < 4) ? src[0][j & 3] : src[1][j & 3]);
            w[1] = (__bf16)((j < 4) ? src[2][j & 3] : src[3][j & 3]);
            *(bf16x2*)(W_ + d * LR + (r2 ^ (d & 56))) = w;
        }
    };

    loadT(pk, baseK, 0);   // tile 0 (pass 0: K only), in flight during Xf load

    // ---- X B-frags straight from global (no LDS staging) ----
    // lane holds X[t = t0 + wv*16 + l16][d = kt*32 + q*8 + j], 16 B/lane/kt
    bf16x8 Xf[2];   // [kt]
    const int row0 = wv * 16;
    {
        const float* pq = baseQ + (size_t)(t0 + row0 + l16) * RS + q * 8;
#pragma unroll
        for (int kt = 0; kt < 2; ++kt) {
            f32x4 f0 = *(const f32x4*)(pq + kt * 32);
            f32x4 f1 = *(const f32x4*)(pq + kt * 32 + 4);
#pragma unroll
            for (int j = 0; j < 4; ++j) {
                Xf[kt][j]     = (__bf16)f0[j];
                Xf[kt][4 + j] = (__bf16)f1[j];
            }
        }
    }

    // permuted K-row base: A-row m of tile mi reads physical K row
    //   (mi>>1)*32 + (m>>2)*8 + (mi&1)*4 + (m&3); per-lane part (m = l16):
    const int rp   = (l16 >> 2) * 8 + (l16 & 3);
    const int kcol = (q * 8) | (((l16 >> 2) & 1) << 5);   // disjoint bits

    const f32x4 zero4 = {0.f, 0.f, 0.f, 0.f};
    f32x4 Y[4];
#pragma unroll
    for (int nd = 0; nd < 4; ++nd) Y[nd] = zero4;

    const int tg = t0 + wv * 16 + l16;

    // ---- prologue: commit tile 0 into buf 0 ----
    commit(ldsK[0], ldsW[0], pk);      // vmcnt wait for pk here (one-time)
    __syncthreads();                   // buf 0 visible

    const int NT = 2 * nP;             // iterations across both passes

    for (int u = 0; u < NT; ++u) {
        const int c  = u & 1;
        const int sb = (u >= nP) ? (u - nP) : u;

        // ---- issue loads for tile u+1 (consumed by commit at iter bottom) ----
        if (u + 1 < NT) {
            const int np_ = (u + 1 >= nP) ? 1 : 0;
            const int nsb = (u + 1) - (np_ ? nP : 0);
            loadT(pk, baseK, nsb * BN);
            if (np_) loadT(pv, baseV, nsb * BN);
        }

        __bf16* K_ = ldsK[c];
        __bf16* W_ = ldsW[c];

        // ---- GEMM1-T (s-permuted): Pt[mi][r] = P[s_l][t],
        //      s_l = (mi>>1)*32 + q*8 + (mi&1)*4 + r
        f32x4 Pt[4];
#pragma unroll
        for (int mi = 0; mi < 4; ++mi) Pt[mi] = zero4;
        __builtin_amdgcn_s_setprio(1);
#pragma unroll
        for (int kt = 0; kt < 2; ++kt) {
#pragma unroll
            for (int mi = 0; mi < 4; ++mi) {
                bf16x8 kf = *(bf16x8*)(K_
                    + ((mi >> 1) * 32 + (mi & 1) * 4 + rp) * LR
                    + ((kt * 32) ^ kcol));
                Pt[mi] = MFMA16(kf, Xf[kt], Pt[mi]);
            }
        }
        __builtin_amdgcn_s_setprio(0);

        // ---- hoist wf reads (independent of GEMM1) -> stream under cvt ----
        bf16x8 wfr[2][4];
#pragma unroll
        for (int kt = 0; kt < 2; ++kt)
#pragma unroll
            for (int nd = 0; nd < 4; ++nd) {
                const int d = l16 + nd * 16;
                wfr[kt][nd] = *(bf16x8*)(W_ + d * LR + ((kt * 32 + q * 8) ^ (d & 56)));
            }

        // ---- in-register masked cvt -> GEMM2 A-frags ----
        // af[kt][b2*4+r] = P[t=l16][s = kt*32 + q*8 + b2*4 + r] (masked)
        bf16x8 af[2];
        {
            const bool diag = (sb == nP - 1);
#pragma unroll
            for (int kt = 0; kt < 2; ++kt) {
                bf16x8 a;
                if (diag) {
#pragma unroll
                    for (int b2 = 0; b2 < 2; ++b2)
#pragma unroll
                        for (int r = 0; r < 4; ++r) {
                            const int sg = sb * BN + kt * 32 + q * 8 + b2 * 4 + r;
                            a[b2 * 4 + r] = (sg <= tg) ? (__bf16)Pt[2 * kt + b2][r]
                                                       : (__bf16)0.0f;
                        }
                } else {
#pragma unroll
                    for (int b2 = 0; b2 < 2; ++b2)
#pragma unroll
                        for (int r = 0; r < 4; ++r)
                            a[b2 * 4 + r] = (__bf16)Pt[2 * kt + b2][r];
                }
                af[kt] = a;
            }
        }

        // ---- GEMM2: Y[t][d] += sum_s P[t][s] W[s][d] ----
        __builtin_amdgcn_s_setprio(1);
#pragma unroll
        for (int kt = 0; kt < 2; ++kt)
#pragma unroll
            for (int nd = 0; nd < 4; ++nd)
                Y[nd] = MFMA16(af[kt], wfr[kt][nd], Y[nd]);
        __builtin_amdgcn_s_setprio(0);

        // ---- pass seam / epilogue ----
        if (u == nP - 1) {
            // seam scratch reuses ldsW[1-c] (dead here: last read behind the
            // iter u-1 barrier; rewritten by this iter's commit below).
            // Wave-private 16-row slice; extra barrier before commit.
            __bf16* sc = ldsW[1 - c] + row0 * LR;
            // o2 (C-layout) -> scratch plain [t][d], reread as frags,
            // Xf = 2Q - o2; then reset Y.
#pragma unroll
            for (int nd = 0; nd < 4; ++nd)
#pragma unroll
                for (int r = 0; r < 4; ++r)
                    sc[(q * 4 + r) * LR + l16 + nd * 16] = (__bf16)Y[nd][r];
#pragma unroll
            for (int kt = 0; kt < 2; ++kt) {
                bf16x8 of = *(bf16x8*)(sc + l16 * LR + kt * 32 + q * 8);
#pragma unroll
                for (int j = 0; j < 8; ++j)
                    Xf[kt][j] = (__bf16)(2.0f * (float)Xf[kt][j] - (float)of[j]);
            }
#pragma unroll
            for (int nd = 0; nd < 4; ++nd) Y[nd] = zero4;
            __syncthreads();   // seam reads done before commit overwrites
        } else if (u == NT - 1) {
            // out[b][t][h][d] fp32
#pragma unroll
            for (int nd = 0; nd < 4; ++nd)
#pragma unroll
                for (int r = 0; r < 4; ++r) {
                    const int t = t0 + wv * 16 + q * 4 + r;
                    const int d = l16 + nd * 16;
                    out[(((size_t)b * S + t) * H + h) * D + d] = Y[nd][r];
                }
        }

        // ---- commit tile u+1 into the other buffer; single barrier ----
        if (u + 1 < NT) {
            commit(ldsK[1 - c], ldsW[1 - c], (u + 1 >= nP) ? pv : pk);
            __syncthreads();
        }
    }
}

extern "C" void kernel_launch(void* const* d_in, const int* in_sizes, int n_in,
                              void* d_out, int out_size, void* d_ws, size_t ws_size,
                              hipStream_t stream)
{
    const float* qkv = (const float*)d_in[0];
    float* out = (float*)d_out;
    ttt_kernel<<<dim3(1024), 256, 0, stream>>>(qkv, out);   // 32 strips x 32 bh
}